// Round 13
// baseline (101.363 us; speedup 1.0000x reference)
//
#include <hip/hip_runtime.h>
#include <math.h>

#define CC   256   // clusters
#define TILE 512   // points per block; 256 threads; 4 points/thread register tile

// float-index offsets in ws
#define OFF_P     0        // 256 x float4: (twok*mu_x, twok*mu_y, twok*mu_z, alpha)
#define OFF_S     2048     // S[256] | Ax[256] | Ay[256] | Az[256]
#define OFF_CD    3072     // 4 doubles: [0]=sumX2 [1]=sumT2 [2]=sumY2
#define OFF_CF    3080     // floats: [0]=twok [1]=lgn
#define OFF_T2    3088     // N floats: per-point log2-normalizer

__device__ __forceinline__ float fexp2(float x) { return __builtin_amdgcn_exp2f(x); }
__device__ __forceinline__ float flog2(float x) { return __builtin_amdgcn_logf(x); }  // v_log_f32 = log2

__global__ __launch_bounds__(256) void gmm_prep(const float* __restrict__ mu,
                                                const float* __restrict__ w,
                                                const float* __restrict__ sigma,
                                                float* __restrict__ ws)
{
    __shared__ float redA[4], redB[4];
    const int c = threadIdx.x;
    const int lane = c & 63, wid = c >> 6;

    // zero per-launch accumulators (stream-ordered before pass1)
    ws[OFF_S + c] = 0.f; ws[OFF_S + 256 + c] = 0.f;
    ws[OFF_S + 512 + c] = 0.f; ws[OFF_S + 768 + c] = 0.f;
    if (c < 4) ((double*)(ws + OFF_CD))[c] = 0.0;

    float wc = w[c];
    float m = wc;
    #pragma unroll
    for (int off = 32; off > 0; off >>= 1) m = fmaxf(m, __shfl_xor(m, off));
    if (lane == 0) redA[wid] = m;
    __syncthreads();
    m = fmaxf(fmaxf(redA[0], redA[1]), fmaxf(redA[2], redA[3]));
    float e = expf(wc - m);
    #pragma unroll
    for (int off = 32; off > 0; off >>= 1) e += __shfl_xor(e, off);
    if (lane == 0) redB[wid] = e;
    __syncthreads();
    float Zw = m + logf(redB[0] + redB[1] + redB[2] + redB[3]);

    const float L = 1.4426950408889634f;   // log2(e)
    float sig = sigma[0];
    float lgn = 3.0f * (logf(sig) + 0.91893853320467274f);
    float k = L / (2.0f * sig * sig);
    float twok = 2.0f * k;
    float mx = mu[3*c], my = mu[3*c+1], mz = mu[3*c+2];
    float m2 = mx*mx + my*my + mz*mz;
    float alpha = (wc - Zw - lgn) * L - k * m2;
    ((float4*)(ws + OFF_P))[c] = make_float4(twok*mx, twok*my, twok*mz, alpha);
    if (c == 0) { ws[OFF_CF + 0] = twok; ws[OFF_CF + 1] = lgn; }
}

__global__ __launch_bounds__(256, 4) void gmm_pass1(const float* __restrict__ X,
                                                    float* __restrict__ ws, int N)
{
    __shared__ float4 Psh[CC];
    __shared__ float4 XT[TILE];        // (x,y,z,T2) for phase B
    __shared__ float2 msP[2][TILE];    // per-half (m,s) partials per point
    __shared__ float4 Bpart[3][CC];    // quarter 1..3 phase-B partials
    __shared__ double redd[2][4];

    const int tid  = threadIdx.x;
    const int pi   = tid & 127;
    const int half = tid >> 7;
    const int n0   = blockIdx.x * TILE;
    const int NT   = min(TILE, N - n0);

    Psh[tid] = ((const float4*)(ws + OFF_P))[tid];

    // 4 register-resident points per thread: pi + 128*j
    float px[4], py[4], pz[4], q2[4];
    bool  vv[4];
    #pragma unroll
    for (int j = 0; j < 4; ++j) {
        const int i = pi + 128*j;
        vv[j] = i < NT;
        float x=0.f, y=0.f, z=0.f;
        if (vv[j]) { const float* p = X + 3*(size_t)(n0+i); x=p[0]; y=p[1]; z=p[2]; }
        px[j]=x; py[j]=y; pz[j]=z;
        q2[j] = fmaf(x,x, fmaf(y,y, z*z));
    }
    __syncthreads();   // Psh ready

    // phase A: 4 points x 128 clusters per thread (half-split), chunk-8 deferred max
    const float4* Pc = Psh + half*128;
    float mm[4] = {-3.0e38f,-3.0e38f,-3.0e38f,-3.0e38f};
    float ss[4] = {0.f,0.f,0.f,0.f};
    for (int c0 = 0; c0 < 128; c0 += 8) {
        float u[4][8];
        #pragma unroll
        for (int jj = 0; jj < 8; ++jj) {
            float4 p = Pc[c0 + jj];
            #pragma unroll
            for (int j = 0; j < 4; ++j)
                u[j][jj] = fmaf(px[j],p.x, fmaf(py[j],p.y, fmaf(pz[j],p.z, p.w)));
        }
        float M[4];
        #pragma unroll
        for (int j = 0; j < 4; ++j) {
            float a = fmaxf(fmaxf(u[j][0],u[j][1]), fmaxf(u[j][2],u[j][3]));
            float b = fmaxf(fmaxf(u[j][4],u[j][5]), fmaxf(u[j][6],u[j][7]));
            M[j] = fmaxf(a, b);
        }
        bool need = (M[0]>mm[0]) || (M[1]>mm[1]) || (M[2]>mm[2]) || (M[3]>mm[3]);
        if (__any(need)) {                  // at most once per chunk
            #pragma unroll
            for (int j = 0; j < 4; ++j) {
                M[j] = fmaxf(M[j], mm[j]);
                ss[j] *= fexp2(mm[j] - M[j]);
                mm[j] = M[j];
            }
        }
        #pragma unroll
        for (int jj = 0; jj < 8; ++jj) {
            #pragma unroll
            for (int j = 0; j < 4; ++j) ss[j] += fexp2(u[j][jj] - mm[j]);
        }
    }
    #pragma unroll
    for (int j = 0; j < 4; ++j) msP[half][pi + 128*j] = make_float2(mm[j], ss[j]);
    __syncthreads();   // msP ready

    // merge halves -> T2; write XT; accumulate sumX2/sumT2 (half0 only; own half in regs)
    double xd = 0.0, td = 0.0;
    if (half == 0) {
        #pragma unroll
        for (int j = 0; j < 4; ++j) {
            if (!vv[j]) continue;
            const int i = pi + 128*j;
            float2 b = msP[1][i];
            float M = fmaxf(mm[j], b.x);
            float T2 = M + flog2(ss[j]*fexp2(mm[j]-M) + b.y*fexp2(b.x-M));
            XT[i] = make_float4(px[j], py[j], pz[j], T2);
            ws[OFF_T2 + n0 + i] = T2;
            xd += (double)q2[j]; td += (double)T2;
        }
    }
    {
        const int lane = tid & 63, wid = tid >> 6;
        #pragma unroll
        for (int off = 32; off > 0; off >>= 1) { xd += __shfl_xor(xd, off); td += __shfl_xor(td, off); }
        if (lane == 0) { redd[0][wid] = xd; redd[1][wid] = td; }
    }
    __syncthreads();   // XT + redd ready
    if (tid == 0) {
        double* CD = (double*)(ws + OFF_CD);
        atomicAdd(CD + 0, redd[0][0]+redd[0][1]+redd[0][2]+redd[0][3]);
        atomicAdd(CD + 1, redd[1][0]+redd[1][1]+redd[1][2]+redd[1][3]);
    }

    // phase B: 4 clusters (ci + 64j) x 128 points (quarter-split, wave-aligned)
    const int q  = tid >> 6;      // quarter (wave index)
    const int ci = tid & 63;
    float4 pc[4];
    #pragma unroll
    for (int j = 0; j < 4; ++j) pc[j] = Psh[ci + 64*j];
    float S[4]={0,0,0,0}, Ax[4]={0,0,0,0}, Ay[4]={0,0,0,0}, Az[4]={0,0,0,0};
    const int nlo = q*128, nhi = min(nlo + 128, NT);
    #pragma unroll 4
    for (int n = nlo; n < nhi; ++n) {
        float4 xt = XT[n];
        #pragma unroll
        for (int j = 0; j < 4; ++j) {
            float u = fmaf(xt.x,pc[j].x, fmaf(xt.y,pc[j].y, fmaf(xt.z,pc[j].z, pc[j].w)));
            float g = fexp2(u - xt.w);
            S[j]+=g; Ax[j]=fmaf(g,xt.x,Ax[j]); Ay[j]=fmaf(g,xt.y,Ay[j]); Az[j]=fmaf(g,xt.z,Az[j]);
        }
    }
    if (q > 0) {
        #pragma unroll
        for (int j = 0; j < 4; ++j)
            Bpart[q-1][ci + 64*j] = make_float4(S[j],Ax[j],Ay[j],Az[j]);
    }
    __syncthreads();   // Bpart ready
    if (q == 0) {
        float* Sg = ws + OFF_S;
        #pragma unroll
        for (int j = 0; j < 4; ++j) {
            const int c = ci + 64*j;
            float4 b0 = Bpart[0][c], b1 = Bpart[1][c], b2 = Bpart[2][c];
            float s  = S[j]  + b0.x + b1.x + b2.x;
            float ax = Ax[j] + b0.y + b1.y + b2.y;
            float ay = Ay[j] + b0.z + b1.z + b2.z;
            float az = Az[j] + b0.w + b1.w + b2.w;
            atomicAdd(Sg       + c, s);
            atomicAdd(Sg + 256 + c, ax);
            atomicAdd(Sg + 512 + c, ay);
            atomicAdd(Sg + 768 + c, az);
        }
    }
}

__global__ __launch_bounds__(256, 4) void gmm_pass3(const float* __restrict__ X,
                                                    float* __restrict__ ws,
                                                    float* __restrict__ out, int N)
{
    __shared__ float4 Psh[CC], Qsh[CC];
    __shared__ float4 Yp[2][TILE];   // per-half partial Y per point
    __shared__ double redd[4];

    const int tid  = threadIdx.x;
    const int pi   = tid & 127;
    const int half = tid >> 7;
    const int n0   = blockIdx.x * TILE;
    const int NT   = min(TILE, N - n0);

    Psh[tid] = ((const float4*)(ws + OFF_P))[tid];
    {   // per-block Q = A / S
        float Sc  = ws[OFF_S       + tid];
        float Axc = ws[OFF_S + 256 + tid];
        float Ayc = ws[OFF_S + 512 + tid];
        float Azc = ws[OFF_S + 768 + tid];
        float inv = 1.0f / fmaxf(Sc, 1e-37f);
        Qsh[tid] = make_float4(Axc*inv, Ayc*inv, Azc*inv, 0.f);
    }

    float px[4], py[4], pz[4], Tn[4];
    bool  vv[4];
    #pragma unroll
    for (int j = 0; j < 4; ++j) {
        const int i = pi + 128*j;
        vv[j] = i < NT;
        float x=0.f,y=0.f,z=0.f,T=0.f;
        if (vv[j]) { const float* p = X + 3*(size_t)(n0+i); x=p[0]; y=p[1]; z=p[2]; T = ws[OFF_T2+n0+i]; }
        px[j]=x; py[j]=y; pz[j]=z; Tn[j]=T;
    }
    __syncthreads();

    // 4 points x 128 clusters per thread (half-split)
    const float4* Pc = Psh + half*128;
    const float4* Qc = Qsh + half*128;
    float Yx[4]={0,0,0,0}, Yy[4]={0,0,0,0}, Yz[4]={0,0,0,0};
    #pragma unroll 4
    for (int c = 0; c < 128; ++c) {
        float4 p = Pc[c];
        float4 qq = Qc[c];
        #pragma unroll
        for (int j = 0; j < 4; ++j) {
            float u = fmaf(px[j],p.x, fmaf(py[j],p.y, fmaf(pz[j],p.z, p.w)));
            float g = fexp2(u - Tn[j]);
            Yx[j]=fmaf(g,qq.x,Yx[j]); Yy[j]=fmaf(g,qq.y,Yy[j]); Yz[j]=fmaf(g,qq.z,Yz[j]);
        }
    }
    #pragma unroll
    for (int j = 0; j < 4; ++j)
        Yp[half][pi + 128*j] = make_float4(Yx[j],Yy[j],Yz[j],0.f);
    __syncthreads();

    double y2d = 0.0;
    if (half == 0) {
        #pragma unroll
        for (int j = 0; j < 4; ++j) {
            if (!vv[j]) continue;
            const int i = pi + 128*j;
            float4 b = Yp[1][i];
            float yx = Yx[j]+b.x, yy = Yy[j]+b.y, yz = Yz[j]+b.z;
            float* op = out + 3*(size_t)(n0+i);
            op[0]=yx; op[1]=yy; op[2]=yz;
            y2d += (double)yx*yx + (double)yy*yy + (double)yz*yz;
        }
    }
    {
        const int lane = tid & 63, wid = tid >> 6;
        #pragma unroll
        for (int off = 32; off > 0; off >>= 1) y2d += __shfl_xor(y2d, off);
        if (lane == 0) redd[wid] = y2d;
    }
    __syncthreads();
    if (tid == 0) atomicAdd(((double*)(ws + OFF_CD)) + 2, redd[0]+redd[1]+redd[2]+redd[3]);
}

// merged cluster reductions + final Cfe (runs after pass3)
__global__ __launch_bounds__(256) void gmm_pass4(float* __restrict__ ws,
                                                 float* __restrict__ cfe_out, int N)
{
    __shared__ double red6[6][4];
    const int c = threadIdx.x;
    const int lane = c & 63, wid = c >> 6;
    const float twok = ws[OFF_CF + 0];
    const double invt = 1.0 / (double)twok;
    double* CD = (double*)(ws + OFF_CD);

    float Sc  = ws[OFF_S       + c];
    float Axc = ws[OFF_S + 256 + c];
    float Ayc = ws[OFF_S + 512 + c];
    float Azc = ws[OFF_S + 768 + c];
    float4 p  = ((const float4*)(ws + OFF_P))[c];   // (twok*mu_old, alpha)

    float inv = 1.0f / fmaxf(Sc, 1e-37f);
    float mx = Axc * inv, my = Ayc * inv, mz = Azc * inv;   // mu_new

    double v0 = (double)Sc;
    double v1 = (double)Sc * (double)(mx*mx + my*my + mz*mz);
    double v2 = (double)Sc * log((double)fmaxf(Sc, 1e-37f));
    double v3 = (double)Sc * (double)(p.x*p.x + p.y*p.y + p.z*p.z);
    double v4 = (double)Sc * (double)p.w;
    double v5 = (double)(p.x*Axc + p.y*Ayc + p.z*Azc);

    #pragma unroll
    for (int off = 32; off > 0; off >>= 1) {
        v0 += __shfl_xor(v0, off); v1 += __shfl_xor(v1, off); v2 += __shfl_xor(v2, off);
        v3 += __shfl_xor(v3, off); v4 += __shfl_xor(v4, off); v5 += __shfl_xor(v5, off);
    }
    if (lane == 0) { red6[0][wid]=v0; red6[1][wid]=v1; red6[2][wid]=v2;
                     red6[3][wid]=v3; red6[4][wid]=v4; red6[5][wid]=v5; }
    __syncthreads();
    if (c == 0) {
        double sumS   = red6[0][0]+red6[0][1]+red6[0][2]+red6[0][3];
        double sumSM2 = red6[1][0]+red6[1][1]+red6[1][2]+red6[1][3];
        double sumSlS = red6[2][0]+red6[2][1]+red6[2][2]+red6[2][3];
        double sumMSs = red6[3][0]+red6[3][1]+red6[3][2]+red6[3][3];   // scaled twok^2
        double sumAS  = red6[4][0]+red6[4][1]+red6[4][2]+red6[4][3];
        double dotMAs = red6[5][0]+red6[5][1]+red6[5][2]+red6[5][3];   // scaled twok
        double sumX2  = CD[0];
        double sumT2  = CD[1];
        double sumY2  = CD[2];
        double sumGD2 = sumX2 + sumMSs*invt*invt - 2.0 * dotMAs*invt;
        double sn2    = sumGD2 / (3.0 * (double)N);
        double sumSlpi = sumSlS - sumS * log(sumS);
        double sumGL2  = sumAS + dotMAs - sumT2;       // log2 units
        double lgn     = (double)ws[OFF_CF + 1];
        double Cfe = (sumSM2 - sumY2) / (2.0 * sn2)
                   + (double)N * lgn
                   + 0.69314718055994531 * sumGL2
                   - sumSlpi;
        cfe_out[0] = (float)Cfe;
    }
}

extern "C" void kernel_launch(void* const* d_in, const int* in_sizes, int n_in,
                              void* d_out, int out_size, void* d_ws, size_t ws_size,
                              hipStream_t stream)
{
    const float* X     = (const float*)d_in[0];
    const float* mu    = (const float*)d_in[1];
    const float* w     = (const float*)d_in[2];
    const float* sigma = (const float*)d_in[3];
    float* out = (float*)d_out;
    float* ws  = (float*)d_ws;
    const int N = in_sizes[0] / 3;
    const int nblk = (N + TILE - 1) / TILE;

    gmm_prep <<<1,    256, 0, stream>>>(mu, w, sigma, ws);
    gmm_pass1<<<nblk, 256, 0, stream>>>(X, ws, N);
    gmm_pass3<<<nblk, 256, 0, stream>>>(X, ws, out, N);
    gmm_pass4<<<1,    256, 0, stream>>>(ws, out + (size_t)3 * N, N);
}